// Round 1
// baseline (2803.393 us; speedup 1.0000x reference)
//
#include <hip/hip_runtime.h>
#include <hip/hip_bf16.h>

#define N_NODES 100000
#define N_EDGES 1600000
#define D 128

// ---------------------------------------------------------------------------
// Kernel 1: support = X @ W   (fp32, vector ALU; no fp32 MFMA on CDNA4)
// Each block: 16 rows of X, full 128x128 W staged in LDS.
// 256 threads: row = t>>4 (16 rows), cg = t&15 (8 consecutive cols each).
// ---------------------------------------------------------------------------
__global__ __launch_bounds__(256) void k_gemm(const float* __restrict__ x,
                                              const float* __restrict__ w,
                                              float* __restrict__ sup) {
    __shared__ float Wl[D][D];        // 64 KB
    __shared__ float Xl[16][132];     // padded (+4) so per-row bank shift of 4

    const int t = threadIdx.x;
    const int row0 = blockIdx.x * 16;

    // Load W (16384 floats) as float4
    const float4* w4 = (const float4*)w;
    float4* Wl4 = (float4*)&Wl[0][0];
    #pragma unroll
    for (int i = t; i < D * D / 4; i += 256) Wl4[i] = w4[i];

    // Load 16 rows of X (float4), into padded LDS rows
    const float4* x4 = (const float4*)(x + (size_t)row0 * D);
    for (int i = t; i < 16 * (D / 4); i += 256) {
        int r = i >> 5, j = i & 31;
        *(float4*)&Xl[r][j * 4] = x4[r * (D / 4) + j];
    }
    __syncthreads();

    const int row = t >> 4;        // 0..15
    const int cg  = t & 15;        // col group: cols cg*8 .. cg*8+7

    float acc[8] = {0.f, 0.f, 0.f, 0.f, 0.f, 0.f, 0.f, 0.f};
    #pragma unroll 4
    for (int k = 0; k < D; ++k) {
        float xv = Xl[row][k];                       // broadcast within lane-groups
        float4 w0 = *(const float4*)&Wl[k][cg * 8];
        float4 w1 = *(const float4*)&Wl[k][cg * 8 + 4];
        acc[0] += xv * w0.x;  acc[1] += xv * w0.y;
        acc[2] += xv * w0.z;  acc[3] += xv * w0.w;
        acc[4] += xv * w1.x;  acc[5] += xv * w1.y;
        acc[6] += xv * w1.z;  acc[7] += xv * w1.w;
    }

    float* o = sup + (size_t)(row0 + row) * D + cg * 8;
    *(float4*)o       = make_float4(acc[0], acc[1], acc[2], acc[3]);
    *(float4*)(o + 4) = make_float4(acc[4], acc[5], acc[6], acc[7]);
}

// ---------------------------------------------------------------------------
// Kernel 2: out[n][d] = bias[d]   (also serves as the per-call re-init since
// the harness does not re-poison/zero d_out between timed replays)
// ---------------------------------------------------------------------------
__global__ __launch_bounds__(256) void k_init(const float* __restrict__ bias,
                                              float* __restrict__ out) {
    __shared__ float4 b4[D / 4];
    if (threadIdx.x < D / 4) b4[threadIdx.x] = ((const float4*)bias)[threadIdx.x];
    __syncthreads();
    const int total = N_NODES * D / 4;   // 3.2M float4
    float4* o4 = (float4*)out;
    for (int i = blockIdx.x * blockDim.x + threadIdx.x; i < total;
         i += gridDim.x * blockDim.x) {
        o4[i] = b4[i & (D / 4 - 1)];
    }
}

// ---------------------------------------------------------------------------
// Kernel 3: COO SpMM scatter: out[row] += val * support[col]
// 32 lanes per edge, float4 gather (512B/edge), scalar f32 atomics to out.
// ---------------------------------------------------------------------------
__global__ __launch_bounds__(256) void k_spmm(const float* __restrict__ sup,
                                              const float* __restrict__ ev,
                                              const int* __restrict__ er,
                                              const int* __restrict__ ec,
                                              float* __restrict__ out) {
    const int eid = blockIdx.x * 8 + (threadIdx.x >> 5);
    if (eid >= N_EDGES) return;
    const int lane = threadIdx.x & 31;

    const int   r = er[eid];
    const int   c = ec[eid];
    const float v = ev[eid];

    float4 s = ((const float4*)(sup + (size_t)c * D))[lane];
    float* o = out + (size_t)r * D + lane * 4;
    atomicAdd(o + 0, v * s.x);
    atomicAdd(o + 1, v * s.y);
    atomicAdd(o + 2, v * s.z);
    atomicAdd(o + 3, v * s.w);
}

extern "C" void kernel_launch(void* const* d_in, const int* in_sizes, int n_in,
                              void* d_out, int out_size, void* d_ws, size_t ws_size,
                              hipStream_t stream) {
    const float* x    = (const float*)d_in[0];
    const float* w    = (const float*)d_in[1];
    const float* bias = (const float*)d_in[2];
    const float* ev   = (const float*)d_in[3];
    const int*   er   = (const int*)d_in[4];
    const int*   ec   = (const int*)d_in[5];
    float* out = (float*)d_out;
    float* sup = (float*)d_ws;   // 100000*128*4 = 51.2 MB scratch

    // support = X @ W
    k_gemm<<<N_NODES / 16, 256, 0, stream>>>(x, w, sup);
    // out = bias (broadcast)  — full overwrite each call
    k_init<<<2048, 256, 0, stream>>>(bias, out);
    // out += A @ support
    k_spmm<<<N_EDGES / 8, 256, 0, stream>>>(sup, ev, er, ec, out);
}

// Round 2
// 439.618 us; speedup vs baseline: 6.3769x; 6.3769x over previous
//
#include <hip/hip_runtime.h>
#include <hip/hip_bf16.h>

#define N_NODES 100000
#define N_EDGES 1600000
#define D 128
#define NBLK 391   // ceil(100000/256) scan blocks

// ---------------------------------------------------------------------------
// Kernel 1: support = X @ W   (fp32 vector ALU; no fp32 MFMA on CDNA4)
// ---------------------------------------------------------------------------
__global__ __launch_bounds__(256) void k_gemm(const float* __restrict__ x,
                                              const float* __restrict__ w,
                                              float* __restrict__ sup) {
    __shared__ float Wl[D][D];        // 64 KB
    __shared__ float Xl[16][132];     // padded

    const int t = threadIdx.x;
    const int row0 = blockIdx.x * 16;

    const float4* w4 = (const float4*)w;
    float4* Wl4 = (float4*)&Wl[0][0];
    #pragma unroll
    for (int i = t; i < D * D / 4; i += 256) Wl4[i] = w4[i];

    const float4* x4 = (const float4*)(x + (size_t)row0 * D);
    for (int i = t; i < 16 * (D / 4); i += 256) {
        int r = i >> 5, j = i & 31;
        *(float4*)&Xl[r][j * 4] = x4[r * (D / 4) + j];
    }
    __syncthreads();

    const int row = t >> 4;
    const int cg  = t & 15;

    float acc[8] = {0.f, 0.f, 0.f, 0.f, 0.f, 0.f, 0.f, 0.f};
    #pragma unroll 4
    for (int k = 0; k < D; ++k) {
        float xv = Xl[row][k];
        float4 w0 = *(const float4*)&Wl[k][cg * 8];
        float4 w1 = *(const float4*)&Wl[k][cg * 8 + 4];
        acc[0] += xv * w0.x;  acc[1] += xv * w0.y;
        acc[2] += xv * w0.z;  acc[3] += xv * w0.w;
        acc[4] += xv * w1.x;  acc[5] += xv * w1.y;
        acc[6] += xv * w1.z;  acc[7] += xv * w1.w;
    }

    float* o = sup + (size_t)(row0 + row) * D + cg * 8;
    *(float4*)o       = make_float4(acc[0], acc[1], acc[2], acc[3]);
    *(float4*)(o + 4) = make_float4(acc[4], acc[5], acc[6], acc[7]);
}

// ---------------------------------------------------------------------------
// CSR build: zero counts -> histogram -> 3-kernel exclusive scan -> scatter
// counts/cursor share one array (scan3 re-zeros it for the scatter pass).
// ---------------------------------------------------------------------------
__global__ __launch_bounds__(256) void k_zero(int* __restrict__ cursor) {
    int i = blockIdx.x * 256 + threadIdx.x;
    if (i < N_NODES) cursor[i] = 0;
}

__global__ __launch_bounds__(256) void k_hist(const int* __restrict__ er,
                                              int* __restrict__ counts) {
    int e = blockIdx.x * 256 + threadIdx.x;
    if (e < N_EDGES) atomicAdd(&counts[er[e]], 1);
}

// block-local inclusive scan; block totals to partials
__global__ __launch_bounds__(256) void k_scan1(const int* __restrict__ counts,
                                               int* __restrict__ incl,
                                               int* __restrict__ partials) {
    __shared__ int s[256];
    int i = blockIdx.x * 256 + threadIdx.x;
    s[threadIdx.x] = (i < N_NODES) ? counts[i] : 0;
    __syncthreads();
    for (int off = 1; off < 256; off <<= 1) {
        int t = (threadIdx.x >= off) ? s[threadIdx.x - off] : 0;
        __syncthreads();
        s[threadIdx.x] += t;
        __syncthreads();
    }
    if (i < N_NODES) incl[i] = s[threadIdx.x];
    if (threadIdx.x == 255) partials[blockIdx.x] = s[255];
}

// single-block scan of the 391 block totals; writes row_start[N] = E total
__global__ __launch_bounds__(512) void k_scan2(int* __restrict__ partials,
                                               int* __restrict__ row_start) {
    __shared__ int s[512];
    int j = threadIdx.x;
    s[j] = (j < NBLK) ? partials[j] : 0;
    __syncthreads();
    for (int off = 1; off < 512; off <<= 1) {
        int t = (j >= off) ? s[j - off] : 0;
        __syncthreads();
        s[j] += t;
        __syncthreads();
    }
    if (j < NBLK) partials[j] = s[j];
    if (j == NBLK - 1) row_start[N_NODES] = s[j];
}

// local-inclusive -> global-exclusive; re-zero counts (becomes scatter cursor)
__global__ __launch_bounds__(256) void k_scan3(int* __restrict__ rs,
                                               int* __restrict__ counts,
                                               const int* __restrict__ partials) {
    int i = blockIdx.x * 256 + threadIdx.x;
    if (i >= N_NODES) return;
    int base = (blockIdx.x > 0) ? partials[blockIdx.x - 1] : 0;
    int c = counts[i];
    rs[i] = base + rs[i] - c;
    counts[i] = 0;
}

__global__ __launch_bounds__(256) void k_scatter(const int* __restrict__ er,
                                                 const int* __restrict__ ec,
                                                 const float* __restrict__ ev,
                                                 const int* __restrict__ row_start,
                                                 int* __restrict__ cursor,
                                                 int* __restrict__ sc,
                                                 float* __restrict__ sv) {
    int e = blockIdx.x * 256 + threadIdx.x;
    if (e >= N_EDGES) return;
    int r = er[e];
    int p = row_start[r] + atomicAdd(&cursor[r], 1);
    sc[p] = ec[e];
    sv[p] = ev[e];
}

// ---------------------------------------------------------------------------
// CSR SpMM: one wave (64 lanes) per output row; float2 per lane; no atomics.
// out[row] = bias + sum_j sv[j] * sup[sc[j]]   — writes each row exactly once,
// which also serves as the per-call re-init of d_out.
// ---------------------------------------------------------------------------
__global__ __launch_bounds__(256) void k_spmm(const float* __restrict__ sup,
                                              const int* __restrict__ row_start,
                                              const int* __restrict__ sc,
                                              const float* __restrict__ sv,
                                              const float* __restrict__ bias,
                                              float* __restrict__ out) {
    const int row = blockIdx.x * 4 + (threadIdx.x >> 6);
    if (row >= N_NODES) return;
    const int lane = threadIdx.x & 63;

    int j   = row_start[row];
    const int end = row_start[row + 1];

    float2 acc = ((const float2*)bias)[lane];

    // 2-edge unroll: two independent gathers in flight
    for (; j + 1 < end; j += 2) {
        int   c0 = sc[j],     c1 = sc[j + 1];
        float v0 = sv[j],     v1 = sv[j + 1];
        float2 s0 = ((const float2*)(sup + (size_t)c0 * D))[lane];
        float2 s1 = ((const float2*)(sup + (size_t)c1 * D))[lane];
        acc.x += v0 * s0.x + v1 * s1.x;
        acc.y += v0 * s0.y + v1 * s1.y;
    }
    if (j < end) {
        int   c = sc[j];
        float v = sv[j];
        float2 s = ((const float2*)(sup + (size_t)c * D))[lane];
        acc.x += v * s.x;
        acc.y += v * s.y;
    }
    ((float2*)(out + (size_t)row * D))[lane] = acc;
}

extern "C" void kernel_launch(void* const* d_in, const int* in_sizes, int n_in,
                              void* d_out, int out_size, void* d_ws, size_t ws_size,
                              hipStream_t stream) {
    const float* x    = (const float*)d_in[0];
    const float* w    = (const float*)d_in[1];
    const float* bias = (const float*)d_in[2];
    const float* ev   = (const float*)d_in[3];
    const int*   er   = (const int*)d_in[4];
    const int*   ec   = (const int*)d_in[5];
    float* out = (float*)d_out;

    // workspace layout (16B aligned), total ~64.8 MB
    char* ws = (char*)d_ws;
    float* sup       = (float*)(ws);                    // 51,200,000 B
    int*   row_start = (int*)  (ws + 51200000);         //    400,016 B (N+1 ints)
    int*   cursor    = (int*)  (ws + 51600016);         //    400,000 B (counts/cursor)
    int*   partials  = (int*)  (ws + 52000016);         //      1,600 B
    int*   sc        = (int*)  (ws + 52001616);         //  6,400,000 B
    float* sv        = (float*)(ws + 58401616);         //  6,400,000 B

    // support = X @ W
    k_gemm<<<N_NODES / 16, 256, 0, stream>>>(x, w, sup);

    // CSR build (overlaps nothing; all on `stream`)
    k_zero   <<<NBLK, 256, 0, stream>>>(cursor);
    k_hist   <<<(N_EDGES + 255) / 256, 256, 0, stream>>>(er, cursor);
    k_scan1  <<<NBLK, 256, 0, stream>>>(cursor, row_start, partials);
    k_scan2  <<<1, 512, 0, stream>>>(partials, row_start);
    k_scan3  <<<NBLK, 256, 0, stream>>>(row_start, cursor, partials);
    k_scatter<<<(N_EDGES + 255) / 256, 256, 0, stream>>>(er, ec, ev, row_start,
                                                         cursor, sc, sv);

    // out = bias + A @ support   (one wave per row, no atomics)
    k_spmm<<<N_NODES / 4, 256, 0, stream>>>(sup, row_start, sc, sv, bias, out);
}

// Round 3
// 252.458 us; speedup vs baseline: 11.1044x; 1.7413x over previous
//
#include <hip/hip_runtime.h>
#include <hip/hip_bf16.h>

#define N_NODES 100000
#define N_EDGES 1600000
#define D 128
#define NBLK 391   // ceil(100000/256)

typedef short  s8v  __attribute__((ext_vector_type(8)));
typedef float  f4v  __attribute__((ext_vector_type(4)));

__device__ __forceinline__ ushort f2bf(float f) {
    uint u = __float_as_uint(f);
    return (ushort)((u + 0x7FFFu + ((u >> 16) & 1u)) >> 16);
}
__device__ __forceinline__ float bflo(uint u) { return __uint_as_float(u << 16); }
__device__ __forceinline__ float bfhi(uint u) { return __uint_as_float(u & 0xFFFF0000u); }

// ---------------------------------------------------------------------------
// W transpose + fp32->bf16:  wt[n][k] = bf16(w[k][n])   (128x128, tiny)
// ---------------------------------------------------------------------------
__global__ __launch_bounds__(256) void k_wt(const float* __restrict__ w,
                                            ushort* __restrict__ wt) {
    int i = blockIdx.x * 256 + threadIdx.x;   // 64 blocks -> 16384 elems
    if (i < D * D) {
        int k = i >> 7, n = i & 127;
        wt[n * D + k] = f2bf(w[i]);
    }
}

// ---------------------------------------------------------------------------
// supb = bf16( X @ W )  via MFMA 16x16x32 bf16.
// Block: 128 rows x 128 cols, 4 waves (each 32 rows x 128 cols).
// A-frags read straight from global fp32 (each elem read exactly once).
// B (Wt) staged in 32KB LDS, XOR-swizzled (^((row&7)<<4)) for conflict-free
// ds_read_b128. Epilogue: acc -> LDS bf16 (swizzled) -> coalesced int4 store.
// ---------------------------------------------------------------------------
__global__ __launch_bounds__(256, 2) void k_gemm(const float* __restrict__ x,
                                                 const ushort* __restrict__ wt,
                                                 ushort* __restrict__ supb) {
    __shared__ int4 Bl4[2048];            // 32 KB
    char* Bl = (char*)Bl4;

    const int t    = threadIdx.x;
    const int lane = t & 63;
    const int w    = t >> 6;
    const int row0 = blockIdx.x * 128;

    // stage Wt -> LDS (swizzled): 2048 16B chunks
    const int4* g = (const int4*)wt;
    #pragma unroll
    for (int i = 0; i < 8; ++i) {
        int idx = t + i * 256;
        int n = idx >> 4, c = idx & 15;
        *(int4*)(Bl + ((n * 256 + c * 16) ^ ((n & 7) << 4))) = g[idx];
    }
    __syncthreads();

    f4v acc[2][8] = {};
    const int arow = row0 + w * 32 + (lane & 15);
    const int kb   = (lane >> 4) * 8;

    #pragma unroll
    for (int ks = 0; ks < 4; ++ks) {
        s8v a[2];
        #pragma unroll
        for (int m = 0; m < 2; ++m) {
            int r = arow + m * 16;
            float4 f0 = make_float4(0.f, 0.f, 0.f, 0.f);
            float4 f1 = make_float4(0.f, 0.f, 0.f, 0.f);
            if (r < N_NODES) {
                const float4* p = (const float4*)(x + (size_t)r * D + ks * 32 + kb);
                f0 = p[0];
                f1 = p[1];
            }
            s8v av;
            av[0] = (short)f2bf(f0.x); av[1] = (short)f2bf(f0.y);
            av[2] = (short)f2bf(f0.z); av[3] = (short)f2bf(f0.w);
            av[4] = (short)f2bf(f1.x); av[5] = (short)f2bf(f1.y);
            av[6] = (short)f2bf(f1.z); av[7] = (short)f2bf(f1.w);
            a[m] = av;
        }
        #pragma unroll
        for (int n = 0; n < 8; ++n) {
            int brow = n * 16 + (lane & 15);
            s8v b = *(s8v*)(Bl + ((brow * 256 + (ks * 32 + kb) * 2) ^ ((brow & 7) << 4)));
            acc[0][n] = __builtin_amdgcn_mfma_f32_16x16x32_bf16(a[0], b, acc[0][n], 0, 0, 0);
            acc[1][n] = __builtin_amdgcn_mfma_f32_16x16x32_bf16(a[1], b, acc[1][n], 0, 0, 0);
        }
    }

    // epilogue: all waves done with Bl -> reuse as per-wave 8KB transpose buf
    __syncthreads();
    char* E = Bl + w * 8192;
    #pragma unroll
    for (int m = 0; m < 2; ++m)
        #pragma unroll
        for (int n = 0; n < 8; ++n)
            #pragma unroll
            for (int r = 0; r < 4; ++r) {
                int rl  = m * 16 + ((lane >> 4) << 2) + r;   // 0..31 within wave
                int col = n * 16 + (lane & 15);
                *(ushort*)(E + ((rl * 256 + col * 2) ^ ((rl & 7) << 4))) =
                    f2bf(acc[m][n][r]);
            }
    __syncthreads();
    #pragma unroll
    for (int i = 0; i < 8; ++i) {
        int idx = lane + i * 64;                  // 0..511
        int rl = idx >> 4, c = idx & 15;
        int4 v = *(int4*)(E + ((rl * 256 + c * 16) ^ ((rl & 7) << 4)));
        int grow = row0 + w * 32 + rl;
        if (grow < N_NODES)
            *(int4*)((char*)supb + (size_t)grow * 256 + c * 16) = v;
    }
}

// ---------------------------------------------------------------------------
// CSR build
// ---------------------------------------------------------------------------
__global__ __launch_bounds__(256) void k_zero(int* __restrict__ cursor) {
    int i = blockIdx.x * 256 + threadIdx.x;
    if (i < N_NODES) cursor[i] = 0;
}

__global__ __launch_bounds__(256) void k_hist(const int* __restrict__ er,
                                              int* __restrict__ counts) {
    int e = blockIdx.x * 256 + threadIdx.x;
    if (e < N_EDGES) atomicAdd(&counts[er[e]], 1);
}

__global__ __launch_bounds__(256) void k_scan1(const int* __restrict__ counts,
                                               int* __restrict__ incl,
                                               int* __restrict__ partials) {
    __shared__ int s[256];
    int i = blockIdx.x * 256 + threadIdx.x;
    s[threadIdx.x] = (i < N_NODES) ? counts[i] : 0;
    __syncthreads();
    for (int off = 1; off < 256; off <<= 1) {
        int t = (threadIdx.x >= off) ? s[threadIdx.x - off] : 0;
        __syncthreads();
        s[threadIdx.x] += t;
        __syncthreads();
    }
    if (i < N_NODES) incl[i] = s[threadIdx.x];
    if (threadIdx.x == 255) partials[blockIdx.x] = s[255];
}

__global__ __launch_bounds__(512) void k_scan2(int* __restrict__ partials,
                                               int* __restrict__ row_start) {
    __shared__ int s[512];
    int j = threadIdx.x;
    s[j] = (j < NBLK) ? partials[j] : 0;
    __syncthreads();
    for (int off = 1; off < 512; off <<= 1) {
        int t = (j >= off) ? s[j - off] : 0;
        __syncthreads();
        s[j] += t;
        __syncthreads();
    }
    if (j < NBLK) partials[j] = s[j];
    if (j == NBLK - 1) row_start[N_NODES] = s[j];
}

__global__ __launch_bounds__(256) void k_scan3(int* __restrict__ rs,
                                               int* __restrict__ counts,
                                               const int* __restrict__ partials) {
    int i = blockIdx.x * 256 + threadIdx.x;
    if (i >= N_NODES) return;
    int base = (blockIdx.x > 0) ? partials[blockIdx.x - 1] : 0;
    int c = counts[i];
    rs[i] = base + rs[i] - c;
    counts[i] = 0;
}

// packed (col, val_bits) -> single 8B scattered store
__global__ __launch_bounds__(256) void k_scatter(const int* __restrict__ er,
                                                 const int* __restrict__ ec,
                                                 const float* __restrict__ ev,
                                                 const int* __restrict__ row_start,
                                                 int* __restrict__ cursor,
                                                 int2* __restrict__ scv) {
    int e = blockIdx.x * 256 + threadIdx.x;
    if (e >= N_EDGES) return;
    int r = er[e];
    int p = row_start[r] + atomicAdd(&cursor[r], 1);
    scv[p] = make_int2(ec[e], __float_as_int(ev[e]));
}

// ---------------------------------------------------------------------------
// CSR SpMM: one wave per row, bf16 gathers (4B/lane), fp32 accum, no atomics.
// out[row] = bias + sum_j val_j * supb[col_j]
// ---------------------------------------------------------------------------
__global__ __launch_bounds__(256) void k_spmm(const ushort* __restrict__ supb,
                                              const int* __restrict__ row_start,
                                              const int2* __restrict__ scv,
                                              const float* __restrict__ bias,
                                              float* __restrict__ out) {
    const int row = blockIdx.x * 4 + (threadIdx.x >> 6);
    if (row >= N_NODES) return;
    const int lane = threadIdx.x & 63;

    int j = row_start[row];
    const int end = row_start[row + 1];

    float2 acc = ((const float2*)bias)[lane];
    const uint* S = (const uint*)supb;   // 64 uints (=128 bf16) per row

    for (; j + 3 < end; j += 4) {
        int2 e0 = scv[j], e1 = scv[j + 1], e2 = scv[j + 2], e3 = scv[j + 3];
        uint s0 = S[(size_t)e0.x * 64 + lane];
        uint s1 = S[(size_t)e1.x * 64 + lane];
        uint s2 = S[(size_t)e2.x * 64 + lane];
        uint s3 = S[(size_t)e3.x * 64 + lane];
        float v0 = __int_as_float(e0.y), v1 = __int_as_float(e1.y);
        float v2 = __int_as_float(e2.y), v3 = __int_as_float(e3.y);
        acc.x += v0 * bflo(s0) + v1 * bflo(s1) + v2 * bflo(s2) + v3 * bflo(s3);
        acc.y += v0 * bfhi(s0) + v1 * bfhi(s1) + v2 * bfhi(s2) + v3 * bfhi(s3);
    }
    for (; j < end; ++j) {
        int2 e = scv[j];
        uint s = S[(size_t)e.x * 64 + lane];
        float v = __int_as_float(e.y);
        acc.x += v * bflo(s);
        acc.y += v * bfhi(s);
    }
    ((float2*)(out + (size_t)row * D))[lane] = acc;
}

extern "C" void kernel_launch(void* const* d_in, const int* in_sizes, int n_in,
                              void* d_out, int out_size, void* d_ws, size_t ws_size,
                              hipStream_t stream) {
    const float* x    = (const float*)d_in[0];
    const float* w    = (const float*)d_in[1];
    const float* bias = (const float*)d_in[2];
    const float* ev   = (const float*)d_in[3];
    const int*   er   = (const int*)d_in[4];
    const int*   ec   = (const int*)d_in[5];
    float* out = (float*)d_out;

    // workspace layout (16B aligned), ~39.2 MB
    char* ws = (char*)d_ws;
    ushort* supb     = (ushort*)(ws);                   // 25,600,000 B
    int*    row_start= (int*)   (ws + 25600000);        //    400,016 B
    int*    cursor   = (int*)   (ws + 26000016);        //    400,000 B
    int*    partials = (int*)   (ws + 26400016);        //      1,616 B
    int2*   scv      = (int2*)  (ws + 26401632);        // 12,800,000 B
    ushort* wt       = (ushort*)(ws + 39201632);        //     32,768 B

    // Wt = bf16(W^T)
    k_wt<<<64, 256, 0, stream>>>(w, wt);
    // supb = bf16(X @ W)
    k_gemm<<<(N_NODES + 127) / 128, 256, 0, stream>>>(x, wt, supb);

    // CSR build
    k_zero   <<<NBLK, 256, 0, stream>>>(cursor);
    k_hist   <<<(N_EDGES + 255) / 256, 256, 0, stream>>>(er, cursor);
    k_scan1  <<<NBLK, 256, 0, stream>>>(cursor, row_start, partials);
    k_scan2  <<<1, 512, 0, stream>>>(partials, row_start);
    k_scan3  <<<NBLK, 256, 0, stream>>>(row_start, cursor, partials);
    k_scatter<<<(N_EDGES + 255) / 256, 256, 0, stream>>>(er, ec, ev, row_start,
                                                         cursor, scv);

    // out = bias + A @ supb
    k_spmm<<<N_NODES / 4, 256, 0, stream>>>(supb, row_start, scv, bias, out);
}